// Round 4
// baseline (211.267 us; speedup 1.0000x reference)
//
#include <hip/hip_runtime.h>
#include <stdint.h>

#define N_ROWS 500000
#define Q0 50000
#define Q1 10000
#define NTILES (N_ROWS / 16)          // 31250 exactly

// ---- replica table layout (BYTES, per replica): bf16 sums + fp32 counts ----
#define S0B_OFF 0
#define S1B_OFF (Q0 * 32)                      // 1,600,000
#define C0B_OFF (S1B_OFF + Q1 * 32)            // 1,920,000
#define C1B_OFF (C0B_OFF + Q0 * 4)             // 2,120,000
#define REP_BYTES (C1B_OFF + Q1 * 4)           // 2,160,000
#define MEANS_FLOATS ((Q0 + Q1) * 16)          // 960,000 fp32 means

typedef __attribute__((ext_vector_type(8))) short bf16x8;   // 8 bf16 (4 VGPRs)
typedef __attribute__((ext_vector_type(4))) float f32x4;

static __device__ __forceinline__ uint32_t f2bfu(float f) {
    uint32_t u = __builtin_bit_cast(uint32_t, f);
    u += 0x7fffu + ((u >> 16) & 1u);          // round-to-nearest-even
    return u >> 16;
}
static __device__ __forceinline__ short f2bf(float f) { return (short)f2bfu(f); }
static __device__ __forceinline__ float bfu2f(uint32_t u) {
    return __builtin_bit_cast(float, u << 16);
}
static __device__ __forceinline__ void pk_add_bf16(uint16_t* addr, uint32_t val) {
    asm volatile("global_atomic_pk_add_bf16 %0, %1, off" :: "v"(addr), "v"(val) : "memory");
}

__global__ __launch_bounds__(256) void zero_ws_kernel(uint32_t* __restrict__ ws, int total) {
    int stride = gridDim.x * 256;
    for (int i = blockIdx.x * 256 + threadIdx.x; i < total; i += stride) ws[i] = 0u;
}

// 4 threads per row (dims q*4..q*4+3): coalesced float4 emb reads, then
// 4 packed-bf16 atomics (2 per table) + 2 count atomics on the q==0 thread.
// Replica chosen by blockIdx&mask (tracks round-robin block->XCD mapping).
__global__ __launch_bounds__(256) void scatter_kernel(const float* __restrict__ emb0,
                                                      const float* __restrict__ emb1,
                                                      const int* __restrict__ z0,
                                                      const int* __restrict__ z1,
                                                      char* __restrict__ ws,
                                                      int rep_mask) {
    int t = blockIdx.x * 256 + threadIdx.x;
    if (t < N_ROWS * 4) {
        int row = t >> 2;
        int q = (t & 3) * 4;
        char* base = ws + (size_t)(blockIdx.x & rep_mask) * REP_BYTES;
        int a0 = z0[row];
        int a1 = z1[row];
        float4 e0 = *(const float4*)(emb0 + (size_t)row * 16 + q);
        float4 e1 = *(const float4*)(emb1 + (size_t)row * 16 + q);
        uint16_t* s0 = (uint16_t*)(base + S0B_OFF) + a0 * 16 + q;
        uint16_t* s1 = (uint16_t*)(base + S1B_OFF) + a1 * 16 + q;
        pk_add_bf16(s0,     f2bfu(e0.x) | (f2bfu(e0.y) << 16));
        pk_add_bf16(s0 + 2, f2bfu(e0.z) | (f2bfu(e0.w) << 16));
        pk_add_bf16(s1,     f2bfu(e1.x) | (f2bfu(e1.y) << 16));
        pk_add_bf16(s1 + 2, f2bfu(e1.z) | (f2bfu(e1.w) << 16));
        if ((t & 3) == 0) {
            atomicAdd((float*)(base + C0B_OFF) + a0, 1.0f);
            atomicAdd((float*)(base + C1B_OFF) + a1, 1.0f);
        }
    }
    // inline-asm atomics aren't tracked by the compiler's final waitcnt — drain.
    asm volatile("s_waitcnt vmcnt(0)" ::: "memory");
}

// Sum bf16 replicas in fp32, divide_no_nan, write fp32 means table.
__global__ __launch_bounds__(256) void finalize_kernel(const char* __restrict__ ws, int reps,
                                                       float* __restrict__ means) {
    int b = blockIdx.x * 256 + threadIdx.x;      // bucket id across both tables
    if (b >= Q0 + Q1) return;
    int inb0 = (b < Q0);
    size_t soff = inb0 ? (S0B_OFF + (size_t)b * 32) : (S1B_OFF + (size_t)(b - Q0) * 32);
    size_t coff = inb0 ? (C0B_OFF + (size_t)b * 4) : (C1B_OFF + (size_t)(b - Q0) * 4);
    float s[16];
#pragma unroll
    for (int i = 0; i < 16; i++) s[i] = 0.0f;
    float c = 0.0f;
    for (int r = 0; r < reps; r++) {
        const char* base = ws + (size_t)r * REP_BYTES;
        const uint32_t* sp = (const uint32_t*)(base + soff);
#pragma unroll
        for (int i = 0; i < 8; i++) {
            uint32_t v = sp[i];
            s[2 * i]     += bfu2f(v & 0xffffu);
            s[2 * i + 1] += bfu2f(v >> 16);
        }
        c += *(const float*)(base + coff);
    }
    float inv = (c > 0.0f) ? (1.0f / c) : 0.0f;   // divide_no_nan
    float4* mp = (float4*)(means + (size_t)b * 16);
#pragma unroll
    for (int i = 0; i < 4; i++) {
        float4 o = {s[4 * i] * inv, s[4 * i + 1] * inv, s[4 * i + 2] * inv, s[4 * i + 3] * inv};
        mp[i] = o;
    }
}

// Fused gather + 3-layer MLP using bf16 MFMA. One wave = one 16-row tile.
__global__ __launch_bounds__(256, 2) void mlp_mfma_kernel(
    const float* __restrict__ X, const int* __restrict__ z0, const int* __restrict__ z1,
    const float* __restrict__ means,
    const float* __restrict__ W1, const float* __restrict__ b1,
    const float* __restrict__ W2, const float* __restrict__ b2,
    const float* __restrict__ Wout, const float* __restrict__ bout,
    float* __restrict__ out)
{
    __shared__ float h1s[4][16 * 128];        // per-wave private transpose buffer (8 KB each)
    const int lane = threadIdx.x & 63;
    const int wv = threadIdx.x >> 6;
    const int c = lane & 15;                  // A-row / B-col / D-col index
    const int g = lane >> 4;                  // k-group
    float* h1w = h1s[wv];

    // ---- build B-fragments for W1 (8 col-tiles x 2 k-steps) and W2 (4 x 4) in registers
    bf16x8 w1f[8][2];
#pragma unroll
    for (int ct = 0; ct < 8; ct++)
#pragma unroll
        for (int ks = 0; ks < 2; ks++)
#pragma unroll
            for (int e = 0; e < 8; e++)
                w1f[ct][ks][e] = f2bf(W1[(ks * 32 + g * 8 + e) * 128 + ct * 16 + c]);

    bf16x8 w2f[4][4];
#pragma unroll
    for (int ct = 0; ct < 4; ct++)
#pragma unroll
        for (int ks = 0; ks < 4; ks++)
#pragma unroll
            for (int e = 0; e < 8; e++)
                w2f[ct][ks][e] = f2bf(W2[(ks * 32 + g * 8 + e) * 64 + ct * 16 + c]);

    float b1v[8], b2v[4], wo[4];
#pragma unroll
    for (int ct = 0; ct < 8; ct++) b1v[ct] = b1[ct * 16 + c];
#pragma unroll
    for (int ct = 0; ct < 4; ct++) b2v[ct] = b2[ct * 16 + c];
#pragma unroll
    for (int t = 0; t < 4; t++) wo[t] = Wout[t * 16 + c];
    const float bo = bout[0];

    // emb-gather routing for the k=32..63 fragment: g<2 -> mean0, g>=2 -> mean1
    const int gg = g * 8;
    const bool is0 = (gg < 16);
    const int* zp = is0 ? z0 : z1;
    const size_t moff = is0 ? 0 : (size_t)Q0 * 16;
    const int esub = gg & 8;

    // ---- swizzled LDS addressing (XOR bits 2-3 of dword index with row&3)
    int waddr[4];                             // write: rows g*4+r, col c (+ct*16 imm)
#pragma unroll
    for (int r = 0; r < 4; r++) {
        int rowl = g * 4 + r;
        waddr[r] = rowl * 128 + (c ^ ((rowl & 3) << 2));
    }
    const int xr = (c & 3) << 2;              // read: row c, feats g*8+e (+ks*32)
    const int lo0 = ((g & 1) << 3) ^ xr;
    const int rbase0 = c * 128 + ((g >> 1) << 4) + lo0;
    const int rbase1 = c * 128 + ((g >> 1) << 4) + (lo0 ^ 4);

    const int wave_id = blockIdx.x * 4 + wv;
    const int nw = gridDim.x * 4;

    for (int tile = wave_id; tile < NTILES; tile += nw) {
        const int row = tile * 16 + c;

        // ---- A1 fragments: k 0..31 from X, k 32..63 from the mean tables
        bf16x8 a1[2];
        const float4* xp = (const float4*)(X + (size_t)row * 32 + gg);
        float4 x0 = xp[0], x1 = xp[1];
        a1[0][0] = f2bf(x0.x); a1[0][1] = f2bf(x0.y);
        a1[0][2] = f2bf(x0.z); a1[0][3] = f2bf(x0.w);
        a1[0][4] = f2bf(x1.x); a1[0][5] = f2bf(x1.y);
        a1[0][6] = f2bf(x1.z); a1[0][7] = f2bf(x1.w);

        int a = zp[row];
        const float4* ep = (const float4*)(means + moff + (size_t)a * 16 + esub);
        float4 e0 = ep[0], e1 = ep[1];
        a1[1][0] = f2bf(e0.x); a1[1][1] = f2bf(e0.y);
        a1[1][2] = f2bf(e0.z); a1[1][3] = f2bf(e0.w);
        a1[1][4] = f2bf(e1.x); a1[1][5] = f2bf(e1.y);
        a1[1][6] = f2bf(e1.z); a1[1][7] = f2bf(e1.w);

        // ---- layer 1: D1[ct] = A1 @ W1[:, ct*16..+16] + b1
        f32x4 d1[8];
#pragma unroll
        for (int ct = 0; ct < 8; ct++) {
            f32x4 acc = {b1v[ct], b1v[ct], b1v[ct], b1v[ct]};
            acc = __builtin_amdgcn_mfma_f32_16x16x32_bf16(a1[0], w1f[ct][0], acc, 0, 0, 0);
            acc = __builtin_amdgcn_mfma_f32_16x16x32_bf16(a1[1], w1f[ct][1], acc, 0, 0, 0);
            d1[ct] = acc;
        }

        // ---- relu + transpose via swizzled LDS (wave-private, no barrier needed)
#pragma unroll
        for (int ct = 0; ct < 8; ct++)
#pragma unroll
            for (int r = 0; r < 4; r++)
                h1w[waddr[r] + ct * 16] = fmaxf(d1[ct][r], 0.0f);

        // ---- A2 fragments from LDS (2 x b128 per k-step, bank-floor-optimal)
        bf16x8 a2[4];
#pragma unroll
        for (int ks = 0; ks < 4; ks++) {
            f32x4 p0 = *(const f32x4*)&h1w[rbase0 + ks * 32];
            f32x4 p1 = *(const f32x4*)&h1w[rbase1 + ks * 32];
            a2[ks][0] = f2bf(p0[0]); a2[ks][1] = f2bf(p0[1]);
            a2[ks][2] = f2bf(p0[2]); a2[ks][3] = f2bf(p0[3]);
            a2[ks][4] = f2bf(p1[0]); a2[ks][5] = f2bf(p1[1]);
            a2[ks][6] = f2bf(p1[2]); a2[ks][7] = f2bf(p1[3]);
        }

        // ---- layer 2: D2[ct] = relu(h1) @ W2[:, ct*16..+16] + b2
        f32x4 d2[4];
#pragma unroll
        for (int ct = 0; ct < 4; ct++) {
            f32x4 acc = {b2v[ct], b2v[ct], b2v[ct], b2v[ct]};
#pragma unroll
            for (int ks = 0; ks < 4; ks++)
                acc = __builtin_amdgcn_mfma_f32_16x16x32_bf16(a2[ks], w2f[ct][ks], acc, 0, 0, 0);
            d2[ct] = acc;
        }

        // ---- layer 3 on VALU + 16-lane butterfly reduce + store
        float sr[4];
#pragma unroll
        for (int r = 0; r < 4; r++) {
            float s = 0.0f;
#pragma unroll
            for (int ct = 0; ct < 4; ct++)
                s = fmaf(fmaxf(d2[ct][r], 0.0f), wo[ct], s);
            sr[r] = s;
        }
#pragma unroll
        for (int m = 1; m <= 8; m <<= 1)
#pragma unroll
            for (int r = 0; r < 4; r++)
                sr[r] += __shfl_xor(sr[r], m);
        if (c == 0) {
            float4 o = {sr[0] + bo, sr[1] + bo, sr[2] + bo, sr[3] + bo};
            *(float4*)(out + tile * 16 + g * 4) = o;
        }
    }
}

extern "C" void kernel_launch(void* const* d_in, const int* in_sizes, int n_in,
                              void* d_out, int out_size, void* d_ws, size_t ws_size,
                              hipStream_t stream) {
    const float* X    = (const float*)d_in[0];
    const int*   z0   = (const int*)d_in[1];
    const int*   z1   = (const int*)d_in[2];
    const float* emb0 = (const float*)d_in[3];
    const float* emb1 = (const float*)d_in[4];
    const float* W1   = (const float*)d_in[5];
    const float* b1   = (const float*)d_in[6];
    const float* W2   = (const float*)d_in[7];
    const float* b2   = (const float*)d_in[8];
    const float* Wout = (const float*)d_in[9];
    const float* bout = (const float*)d_in[10];
    float* out = (float*)d_out;
    char* ws  = (char*)d_ws;

    // Deterministic host-side replica count from ws_size: 8 -> 4 -> 2 -> 1.
    int R = 1;
    while (R < 8 &&
           (size_t)(R * 2) * REP_BYTES + (size_t)MEANS_FLOATS * 4 <= ws_size) R <<= 1;
    float* means = (float*)(ws + (size_t)R * REP_BYTES);

    zero_ws_kernel<<<2048, 256, 0, stream>>>((uint32_t*)ws, R * (REP_BYTES / 4));
    scatter_kernel<<<(N_ROWS * 4 + 255) / 256, 256, 0, stream>>>(emb0, emb1, z0, z1, ws, R - 1);
    finalize_kernel<<<(Q0 + Q1 + 255) / 256, 256, 0, stream>>>(ws, R, means);
    mlp_mfma_kernel<<<512, 256, 0, stream>>>(X, z0, z1, means, W1, b1, W2, b2, Wout, bout, out);
}

// Round 5
// 151.903 us; speedup vs baseline: 1.3908x; 1.3908x over previous
//
#include <hip/hip_runtime.h>
#include <stdint.h>

#define N_ROWS 500000
#define Q0 50000
#define Q1 10000
#define NB (Q0 + Q1)
#define NTILES (N_ROWS / 16)          // 31250 exactly

typedef __attribute__((ext_vector_type(8))) short bf16x8;   // 8 bf16 (4 VGPRs)
typedef __attribute__((ext_vector_type(4))) float f32x4;

static __device__ __forceinline__ uint32_t f2bfu(float f) {
    uint32_t u = __builtin_bit_cast(uint32_t, f);
    u += 0x7fffu + ((u >> 16) & 1u);          // round-to-nearest-even
    return u >> 16;
}
static __device__ __forceinline__ short f2bf(float f) { return (short)f2bfu(f); }

__global__ __launch_bounds__(256) void zero_ws_kernel(uint32_t* __restrict__ p, int total) {
    int stride = gridDim.x * 256;
    for (int i = blockIdx.x * 256 + threadIdx.x; i < total; i += stride) p[i] = 0u;
}

// One thread per row: 2 int atomics (cursor fetch-add) + 2 list writes.
// Rare overflow (slot >= cap) falls back to fp32 atomic adds into ovf table,
// keeping the result correct for ANY input distribution.
__global__ __launch_bounds__(256) void bin_kernel(const int* __restrict__ z0,
                                                  const int* __restrict__ z1,
                                                  const float* __restrict__ emb0,
                                                  const float* __restrict__ emb1,
                                                  int* __restrict__ list0,
                                                  int* __restrict__ list1,
                                                  int* __restrict__ cur0,
                                                  int* __restrict__ cur1,
                                                  float* __restrict__ ovf,
                                                  int cap0, int cap1) {
    int row = blockIdx.x * 256 + threadIdx.x;
    if (row >= N_ROWS) return;
    int a0 = z0[row];
    int s0 = atomicAdd(cur0 + a0, 1);
    if (s0 < cap0) {
        list0[a0 * cap0 + s0] = row;
    } else {
        const float* e = emb0 + (size_t)row * 16;
        for (int d = 0; d < 16; d++) atomicAdd(ovf + (size_t)a0 * 16 + d, e[d]);
    }
    int a1 = z1[row];
    int s1 = atomicAdd(cur1 + a1, 1);
    if (s1 < cap1) {
        list1[a1 * cap1 + s1] = row;
    } else {
        const float* e = emb1 + (size_t)row * 16;
        for (int d = 0; d < 16; d++) atomicAdd(ovf + (size_t)(Q0 + a1) * 16 + d, e[d]);
    }
}

// One wave per bucket: gather member rows (4 rows x 16 dims per step, 2-way
// unrolled), accumulate fp32 in registers, divide_no_nan, write fp32 mean.
__global__ __launch_bounds__(256) void reduce_kernel(const float* __restrict__ emb0,
                                                     const float* __restrict__ emb1,
                                                     const int* __restrict__ list0,
                                                     const int* __restrict__ list1,
                                                     const int* __restrict__ cur0,
                                                     const int* __restrict__ cur1,
                                                     const float* __restrict__ ovf,
                                                     float* __restrict__ means,
                                                     int cap0, int cap1) {
    int w = (blockIdx.x * 256 + threadIdx.x) >> 6;     // global wave id = bucket id
    if (w >= NB) return;
    const int lane = threadIdx.x & 63;
    const int c = lane & 15;
    const int g = lane >> 4;

    const bool t0 = (w < Q0);
    const int b = t0 ? w : (w - Q0);
    const int cap = t0 ? cap0 : cap1;
    const int* list = (t0 ? list0 : list1) + (size_t)b * cap;
    const float* emb = t0 ? emb0 : emb1;
    const int cnt = t0 ? cur0[b] : cur1[b];
    const int n = cnt < cap ? cnt : cap;

    float s0 = 0.0f, s1 = 0.0f;
    for (int i = 0; i < n; i += 8) {
        int i0 = i + g;
        int i1 = i + 4 + g;
        if (i0 < n) s0 += emb[(size_t)list[i0] * 16 + c];
        if (i1 < n) s1 += emb[(size_t)list[i1] * 16 + c];
    }
    float s = s0 + s1;
    if (g == 0) s += ovf[(size_t)w * 16 + c];          // overflow contribution (usually 0)
    s += __shfl_xor(s, 16);
    s += __shfl_xor(s, 32);
    float inv = (cnt > 0) ? (1.0f / (float)cnt) : 0.0f;   // divide_no_nan
    if (g == 0) means[(size_t)w * 16 + c] = s * inv;
}

// Fused gather + 3-layer MLP using bf16 MFMA. One wave = one 16-row tile.
__global__ __launch_bounds__(256, 2) void mlp_mfma_kernel(
    const float* __restrict__ X, const int* __restrict__ z0, const int* __restrict__ z1,
    const float* __restrict__ means,
    const float* __restrict__ W1, const float* __restrict__ b1,
    const float* __restrict__ W2, const float* __restrict__ b2,
    const float* __restrict__ Wout, const float* __restrict__ bout,
    float* __restrict__ out)
{
    __shared__ float h1s[4][16 * 128];        // per-wave private transpose buffer (8 KB each)
    const int lane = threadIdx.x & 63;
    const int wv = threadIdx.x >> 6;
    const int c = lane & 15;                  // A-row / B-col / D-col index
    const int g = lane >> 4;                  // k-group
    float* h1w = h1s[wv];

    // ---- build B-fragments for W1 (8 col-tiles x 2 k-steps) and W2 (4 x 4) in registers
    bf16x8 w1f[8][2];
#pragma unroll
    for (int ct = 0; ct < 8; ct++)
#pragma unroll
        for (int ks = 0; ks < 2; ks++)
#pragma unroll
            for (int e = 0; e < 8; e++)
                w1f[ct][ks][e] = f2bf(W1[(ks * 32 + g * 8 + e) * 128 + ct * 16 + c]);

    bf16x8 w2f[4][4];
#pragma unroll
    for (int ct = 0; ct < 4; ct++)
#pragma unroll
        for (int ks = 0; ks < 4; ks++)
#pragma unroll
            for (int e = 0; e < 8; e++)
                w2f[ct][ks][e] = f2bf(W2[(ks * 32 + g * 8 + e) * 64 + ct * 16 + c]);

    float b1v[8], b2v[4], wo[4];
#pragma unroll
    for (int ct = 0; ct < 8; ct++) b1v[ct] = b1[ct * 16 + c];
#pragma unroll
    for (int ct = 0; ct < 4; ct++) b2v[ct] = b2[ct * 16 + c];
#pragma unroll
    for (int t = 0; t < 4; t++) wo[t] = Wout[t * 16 + c];
    const float bo = bout[0];

    // emb-gather routing for the k=32..63 fragment: g<2 -> mean0, g>=2 -> mean1
    const int gg = g * 8;
    const bool is0 = (gg < 16);
    const int* zp = is0 ? z0 : z1;
    const size_t moff = is0 ? 0 : (size_t)Q0 * 16;
    const int esub = gg & 8;

    // ---- swizzled LDS addressing (XOR bits 2-3 of dword index with row&3)
    int waddr[4];                             // write: rows g*4+r, col c (+ct*16 imm)
#pragma unroll
    for (int r = 0; r < 4; r++) {
        int rowl = g * 4 + r;
        waddr[r] = rowl * 128 + (c ^ ((rowl & 3) << 2));
    }
    const int xr = (c & 3) << 2;              // read: row c, feats g*8+e (+ks*32)
    const int lo0 = ((g & 1) << 3) ^ xr;
    const int rbase0 = c * 128 + ((g >> 1) << 4) + lo0;
    const int rbase1 = c * 128 + ((g >> 1) << 4) + (lo0 ^ 4);

    const int wave_id = blockIdx.x * 4 + wv;
    const int nw = gridDim.x * 4;

    for (int tile = wave_id; tile < NTILES; tile += nw) {
        const int row = tile * 16 + c;

        // ---- A1 fragments: k 0..31 from X, k 32..63 from the mean tables
        bf16x8 a1[2];
        const float4* xp = (const float4*)(X + (size_t)row * 32 + gg);
        float4 x0 = xp[0], x1 = xp[1];
        a1[0][0] = f2bf(x0.x); a1[0][1] = f2bf(x0.y);
        a1[0][2] = f2bf(x0.z); a1[0][3] = f2bf(x0.w);
        a1[0][4] = f2bf(x1.x); a1[0][5] = f2bf(x1.y);
        a1[0][6] = f2bf(x1.z); a1[0][7] = f2bf(x1.w);

        int a = zp[row];
        const float4* ep = (const float4*)(means + moff + (size_t)a * 16 + esub);
        float4 e0 = ep[0], e1 = ep[1];
        a1[1][0] = f2bf(e0.x); a1[1][1] = f2bf(e0.y);
        a1[1][2] = f2bf(e0.z); a1[1][3] = f2bf(e0.w);
        a1[1][4] = f2bf(e1.x); a1[1][5] = f2bf(e1.y);
        a1[1][6] = f2bf(e1.z); a1[1][7] = f2bf(e1.w);

        // ---- layer 1: D1[ct] = A1 @ W1[:, ct*16..+16] + b1
        f32x4 d1[8];
#pragma unroll
        for (int ct = 0; ct < 8; ct++) {
            f32x4 acc = {b1v[ct], b1v[ct], b1v[ct], b1v[ct]};
            acc = __builtin_amdgcn_mfma_f32_16x16x32_bf16(a1[0], w1f[ct][0], acc, 0, 0, 0);
            acc = __builtin_amdgcn_mfma_f32_16x16x32_bf16(a1[1], w1f[ct][1], acc, 0, 0, 0);
            d1[ct] = acc;
        }

        // ---- relu + transpose via swizzled LDS (wave-private, no barrier needed)
#pragma unroll
        for (int ct = 0; ct < 8; ct++)
#pragma unroll
            for (int r = 0; r < 4; r++)
                h1w[waddr[r] + ct * 16] = fmaxf(d1[ct][r], 0.0f);

        // ---- A2 fragments from LDS (2 x b128 per k-step, bank-floor-optimal)
        bf16x8 a2[4];
#pragma unroll
        for (int ks = 0; ks < 4; ks++) {
            f32x4 p0 = *(const f32x4*)&h1w[rbase0 + ks * 32];
            f32x4 p1 = *(const f32x4*)&h1w[rbase1 + ks * 32];
            a2[ks][0] = f2bf(p0[0]); a2[ks][1] = f2bf(p0[1]);
            a2[ks][2] = f2bf(p0[2]); a2[ks][3] = f2bf(p0[3]);
            a2[ks][4] = f2bf(p1[0]); a2[ks][5] = f2bf(p1[1]);
            a2[ks][6] = f2bf(p1[2]); a2[ks][7] = f2bf(p1[3]);
        }

        // ---- layer 2: D2[ct] = relu(h1) @ W2[:, ct*16..+16] + b2
        f32x4 d2[4];
#pragma unroll
        for (int ct = 0; ct < 4; ct++) {
            f32x4 acc = {b2v[ct], b2v[ct], b2v[ct], b2v[ct]};
#pragma unroll
            for (int ks = 0; ks < 4; ks++)
                acc = __builtin_amdgcn_mfma_f32_16x16x32_bf16(a2[ks], w2f[ct][ks], acc, 0, 0, 0);
            d2[ct] = acc;
        }

        // ---- layer 3 on VALU + 16-lane butterfly reduce + store
        float sr[4];
#pragma unroll
        for (int r = 0; r < 4; r++) {
            float s = 0.0f;
#pragma unroll
            for (int ct = 0; ct < 4; ct++)
                s = fmaf(fmaxf(d2[ct][r], 0.0f), wo[ct], s);
            sr[r] = s;
        }
#pragma unroll
        for (int m = 1; m <= 8; m <<= 1)
#pragma unroll
            for (int r = 0; r < 4; r++)
                sr[r] += __shfl_xor(sr[r], m);
        if (c == 0) {
            float4 o = {sr[0] + bo, sr[1] + bo, sr[2] + bo, sr[3] + bo};
            *(float4*)(out + tile * 16 + g * 4) = o;
        }
    }
}

extern "C" void kernel_launch(void* const* d_in, const int* in_sizes, int n_in,
                              void* d_out, int out_size, void* d_ws, size_t ws_size,
                              hipStream_t stream) {
    const float* X    = (const float*)d_in[0];
    const int*   z0   = (const int*)d_in[1];
    const int*   z1   = (const int*)d_in[2];
    const float* emb0 = (const float*)d_in[3];
    const float* emb1 = (const float*)d_in[4];
    const float* W1   = (const float*)d_in[5];
    const float* b1   = (const float*)d_in[6];
    const float* W2   = (const float*)d_in[7];
    const float* b2   = (const float*)d_in[8];
    const float* Wout = (const float*)d_in[9];
    const float* bout = (const float*)d_in[10];
    float* out = (float*)d_out;
    char* ws = (char*)d_ws;

    // Fixed region: cursors (NB ints) + ovf (NB*16 f32) + means (NB*16 f32).
    const size_t fixed = (size_t)NB * 4 + (size_t)NB * 64 * 2;
    // Capacity ladder (deterministic, host-side): overflow path keeps any choice correct.
    int CAP0 = 8, CAP1 = 16;
    const int c0s[4] = {64, 32, 16, 8};
    const int c1s[4] = {128, 64, 32, 16};
    for (int i = 0; i < 4; i++) {
        size_t need = fixed + ((size_t)Q0 * c0s[i] + (size_t)Q1 * c1s[i]) * 4;
        if (need <= ws_size) { CAP0 = c0s[i]; CAP1 = c1s[i]; break; }
    }

    char* p = ws;
    int* list0 = (int*)p;      p += (size_t)Q0 * CAP0 * 4;
    int* list1 = (int*)p;      p += (size_t)Q1 * CAP1 * 4;
    uint32_t* zbase = (uint32_t*)p;
    int* cur0 = (int*)p;       p += (size_t)Q0 * 4;
    int* cur1 = (int*)p;       p += (size_t)Q1 * 4;
    float* ovf = (float*)p;    p += (size_t)NB * 64;
    float* means = (float*)p;

    const int zero_dwords = NB + NB * 16;    // cursors + ovf
    zero_ws_kernel<<<1024, 256, 0, stream>>>(zbase, zero_dwords);
    bin_kernel<<<(N_ROWS + 255) / 256, 256, 0, stream>>>(z0, z1, emb0, emb1,
                                                         list0, list1, cur0, cur1, ovf,
                                                         CAP0, CAP1);
    reduce_kernel<<<(NB * 64 + 255) / 256, 256, 0, stream>>>(emb0, emb1, list0, list1,
                                                             cur0, cur1, ovf, means,
                                                             CAP0, CAP1);
    mlp_mfma_kernel<<<512, 256, 0, stream>>>(X, z0, z1, means, W1, b1, W2, b2,
                                             Wout, bout, out);
}

// Round 6
// 126.914 us; speedup vs baseline: 1.6646x; 1.1969x over previous
//
#include <hip/hip_runtime.h>
#include <stdint.h>

#define N_ROWS 500000
#define Q0 50000
#define Q1 10000
#define NB (Q0 + Q1)
#define NTILES (N_ROWS / 16)          // 31250 exactly

typedef __attribute__((ext_vector_type(8))) short bf16x8;   // 8 bf16 (4 VGPRs)
typedef __attribute__((ext_vector_type(4))) float f32x4;

static __device__ __forceinline__ uint32_t f2bfu(float f) {
    uint32_t u = __builtin_bit_cast(uint32_t, f);
    u += 0x7fffu + ((u >> 16) & 1u);          // round-to-nearest-even
    return u >> 16;
}
static __device__ __forceinline__ short f2bf(float f) { return (short)f2bfu(f); }
static __device__ __forceinline__ float bfu2f(uint32_t u) {
    return __builtin_bit_cast(float, u << 16);
}
static __device__ __forceinline__ uint32_t pk2(float x, float y) {
    return f2bfu(x) | (f2bfu(y) << 16);
}

__global__ __launch_bounds__(256) void zero_ws_kernel(uint32_t* __restrict__ p, int total) {
    int stride = gridDim.x * 256;
    for (int i = blockIdx.x * 256 + threadIdx.x; i < total; i += stride) p[i] = 0u;
}

// One thread per row: cursor fetch-add per table, then store the row's emb data
// (16 dims as bf16 = 32B) directly into its bucket slot. The scattered-line
// traffic (paid regardless) now CARRIES the payload, and the later reduce reads
// sequentially. Overflow (slot >= cap) falls back to fp32 atomics into ovf,
// keeping any input distribution correct.
__global__ __launch_bounds__(256) void bin_kernel(const int* __restrict__ z0,
                                                  const int* __restrict__ z1,
                                                  const float* __restrict__ emb0,
                                                  const float* __restrict__ emb1,
                                                  uint32_t* __restrict__ bins0,
                                                  uint32_t* __restrict__ bins1,
                                                  int* __restrict__ cur0,
                                                  int* __restrict__ cur1,
                                                  float* __restrict__ ovf,
                                                  int cap0, int cap1) {
    int row = blockIdx.x * 256 + threadIdx.x;
    if (row >= N_ROWS) return;
    int a0 = z0[row];
    int a1 = z1[row];
    int s0 = atomicAdd(cur0 + a0, 1);          // issue both atomics early; emb
    int s1 = atomicAdd(cur1 + a1, 1);          // loads overlap their latency
    const float4* e0 = (const float4*)(emb0 + (size_t)row * 16);
    const float4* e1 = (const float4*)(emb1 + (size_t)row * 16);
    float4 A = e0[0], B = e0[1], C = e0[2], D = e0[3];
    float4 E = e1[0], F = e1[1], G = e1[2], H = e1[3];

    if (s0 < cap0) {
        uint4 lo = {pk2(A.x, A.y), pk2(A.z, A.w), pk2(B.x, B.y), pk2(B.z, B.w)};
        uint4 hi = {pk2(C.x, C.y), pk2(C.z, C.w), pk2(D.x, D.y), pk2(D.z, D.w)};
        uint4* d = (uint4*)(bins0 + ((size_t)a0 * cap0 + s0) * 8);
        d[0] = lo; d[1] = hi;
    } else {
        float* o = ovf + (size_t)a0 * 16;
        atomicAdd(o + 0, A.x);  atomicAdd(o + 1, A.y);  atomicAdd(o + 2, A.z);  atomicAdd(o + 3, A.w);
        atomicAdd(o + 4, B.x);  atomicAdd(o + 5, B.y);  atomicAdd(o + 6, B.z);  atomicAdd(o + 7, B.w);
        atomicAdd(o + 8, C.x);  atomicAdd(o + 9, C.y);  atomicAdd(o + 10, C.z); atomicAdd(o + 11, C.w);
        atomicAdd(o + 12, D.x); atomicAdd(o + 13, D.y); atomicAdd(o + 14, D.z); atomicAdd(o + 15, D.w);
    }
    if (s1 < cap1) {
        uint4 lo = {pk2(E.x, E.y), pk2(E.z, E.w), pk2(F.x, F.y), pk2(F.z, F.w)};
        uint4 hi = {pk2(G.x, G.y), pk2(G.z, G.w), pk2(H.x, H.y), pk2(H.z, H.w)};
        uint4* d = (uint4*)(bins1 + ((size_t)a1 * cap1 + s1) * 8);
        d[0] = lo; d[1] = hi;
    } else {
        float* o = ovf + (size_t)(Q0 + a1) * 16;
        atomicAdd(o + 0, E.x);  atomicAdd(o + 1, E.y);  atomicAdd(o + 2, E.z);  atomicAdd(o + 3, E.w);
        atomicAdd(o + 4, F.x);  atomicAdd(o + 5, F.y);  atomicAdd(o + 6, F.z);  atomicAdd(o + 7, F.w);
        atomicAdd(o + 8, G.x);  atomicAdd(o + 9, G.y);  atomicAdd(o + 10, G.z); atomicAdd(o + 11, G.w);
        atomicAdd(o + 12, H.x); atomicAdd(o + 13, H.y); atomicAdd(o + 14, H.z); atomicAdd(o + 15, H.w);
    }
}

// One wave per bucket: sequential burst-read of the bucket's valid slot prefix.
// Lane layout: sg = lane>>3 (slot within group of 8), pr = lane&7 (dword pair).
// A wave-load covers 8 slots x 32B = 256B contiguous. 2-way unrolled (16 slots
// in flight). Cross-lane reduce over sg, then 8 lanes write the fp32 mean.
__global__ __launch_bounds__(256) void reduce_kernel(const uint32_t* __restrict__ bins0,
                                                     const uint32_t* __restrict__ bins1,
                                                     const int* __restrict__ cur0,
                                                     const int* __restrict__ cur1,
                                                     const float* __restrict__ ovf,
                                                     float* __restrict__ means,
                                                     int cap0, int cap1) {
    int w = (blockIdx.x * 256 + threadIdx.x) >> 6;     // global wave id = bucket id
    if (w >= NB) return;
    const int lane = threadIdx.x & 63;
    const int sg = lane >> 3;
    const int pr = lane & 7;

    const bool t0 = (w < Q0);
    const int b = t0 ? w : (w - Q0);
    const int cap = t0 ? cap0 : cap1;
    const uint32_t* bins = (t0 ? bins0 : bins1) + (size_t)b * cap * 8;
    const int cnt = t0 ? cur0[b] : cur1[b];
    const int n = cnt < cap ? cnt : cap;

    float sa = 0.0f, sb = 0.0f;
    for (int i = 0; i < n; i += 16) {
        int u = i + sg;
        int v = i + 8 + sg;
        if (u < n) {
            uint32_t x = bins[(size_t)u * 8 + pr];
            sa += bfu2f(x & 0xffffu);
            sb += bfu2f(x >> 16);
        }
        if (v < n) {
            uint32_t x = bins[(size_t)v * 8 + pr];
            sa += bfu2f(x & 0xffffu);
            sb += bfu2f(x >> 16);
        }
    }
#pragma unroll
    for (int m = 8; m <= 32; m <<= 1) {
        sa += __shfl_xor(sa, m);
        sb += __shfl_xor(sb, m);
    }
    if (sg == 0) {
        sa += ovf[(size_t)w * 16 + pr * 2];            // overflow contribution (usually 0)
        sb += ovf[(size_t)w * 16 + pr * 2 + 1];
        float inv = (cnt > 0) ? (1.0f / (float)cnt) : 0.0f;   // divide_no_nan
        float2 o = {sa * inv, sb * inv};
        *(float2*)(means + (size_t)w * 16 + pr * 2) = o;
    }
}

// Fused gather + 3-layer MLP using bf16 MFMA. One wave = one 16-row tile.
__global__ __launch_bounds__(256, 2) void mlp_mfma_kernel(
    const float* __restrict__ X, const int* __restrict__ z0, const int* __restrict__ z1,
    const float* __restrict__ means,
    const float* __restrict__ W1, const float* __restrict__ b1,
    const float* __restrict__ W2, const float* __restrict__ b2,
    const float* __restrict__ Wout, const float* __restrict__ bout,
    float* __restrict__ out)
{
    __shared__ float h1s[4][16 * 128];        // per-wave private transpose buffer (8 KB each)
    const int lane = threadIdx.x & 63;
    const int wv = threadIdx.x >> 6;
    const int c = lane & 15;                  // A-row / B-col / D-col index
    const int g = lane >> 4;                  // k-group
    float* h1w = h1s[wv];

    // ---- build B-fragments for W1 (8 col-tiles x 2 k-steps) and W2 (4 x 4) in registers
    bf16x8 w1f[8][2];
#pragma unroll
    for (int ct = 0; ct < 8; ct++)
#pragma unroll
        for (int ks = 0; ks < 2; ks++)
#pragma unroll
            for (int e = 0; e < 8; e++)
                w1f[ct][ks][e] = f2bf(W1[(ks * 32 + g * 8 + e) * 128 + ct * 16 + c]);

    bf16x8 w2f[4][4];
#pragma unroll
    for (int ct = 0; ct < 4; ct++)
#pragma unroll
        for (int ks = 0; ks < 4; ks++)
#pragma unroll
            for (int e = 0; e < 8; e++)
                w2f[ct][ks][e] = f2bf(W2[(ks * 32 + g * 8 + e) * 64 + ct * 16 + c]);

    float b1v[8], b2v[4], wo[4];
#pragma unroll
    for (int ct = 0; ct < 8; ct++) b1v[ct] = b1[ct * 16 + c];
#pragma unroll
    for (int ct = 0; ct < 4; ct++) b2v[ct] = b2[ct * 16 + c];
#pragma unroll
    for (int t = 0; t < 4; t++) wo[t] = Wout[t * 16 + c];
    const float bo = bout[0];

    // emb-gather routing for the k=32..63 fragment: g<2 -> mean0, g>=2 -> mean1
    const int gg = g * 8;
    const bool is0 = (gg < 16);
    const int* zp = is0 ? z0 : z1;
    const size_t moff = is0 ? 0 : (size_t)Q0 * 16;
    const int esub = gg & 8;

    // ---- swizzled LDS addressing (XOR bits 2-3 of dword index with row&3)
    int waddr[4];                             // write: rows g*4+r, col c (+ct*16 imm)
#pragma unroll
    for (int r = 0; r < 4; r++) {
        int rowl = g * 4 + r;
        waddr[r] = rowl * 128 + (c ^ ((rowl & 3) << 2));
    }
    const int xr = (c & 3) << 2;              // read: row c, feats g*8+e (+ks*32)
    const int lo0 = ((g & 1) << 3) ^ xr;
    const int rbase0 = c * 128 + ((g >> 1) << 4) + lo0;
    const int rbase1 = c * 128 + ((g >> 1) << 4) + (lo0 ^ 4);

    const int wave_id = blockIdx.x * 4 + wv;
    const int nw = gridDim.x * 4;

    for (int tile = wave_id; tile < NTILES; tile += nw) {
        const int row = tile * 16 + c;

        // ---- A1 fragments: k 0..31 from X, k 32..63 from the mean tables
        bf16x8 a1[2];
        const float4* xp = (const float4*)(X + (size_t)row * 32 + gg);
        float4 x0 = xp[0], x1 = xp[1];
        a1[0][0] = f2bf(x0.x); a1[0][1] = f2bf(x0.y);
        a1[0][2] = f2bf(x0.z); a1[0][3] = f2bf(x0.w);
        a1[0][4] = f2bf(x1.x); a1[0][5] = f2bf(x1.y);
        a1[0][6] = f2bf(x1.z); a1[0][7] = f2bf(x1.w);

        int a = zp[row];
        const float4* ep = (const float4*)(means + moff + (size_t)a * 16 + esub);
        float4 e0 = ep[0], e1 = ep[1];
        a1[1][0] = f2bf(e0.x); a1[1][1] = f2bf(e0.y);
        a1[1][2] = f2bf(e0.z); a1[1][3] = f2bf(e0.w);
        a1[1][4] = f2bf(e1.x); a1[1][5] = f2bf(e1.y);
        a1[1][6] = f2bf(e1.z); a1[1][7] = f2bf(e1.w);

        // ---- layer 1: D1[ct] = A1 @ W1[:, ct*16..+16] + b1
        f32x4 d1[8];
#pragma unroll
        for (int ct = 0; ct < 8; ct++) {
            f32x4 acc = {b1v[ct], b1v[ct], b1v[ct], b1v[ct]};
            acc = __builtin_amdgcn_mfma_f32_16x16x32_bf16(a1[0], w1f[ct][0], acc, 0, 0, 0);
            acc = __builtin_amdgcn_mfma_f32_16x16x32_bf16(a1[1], w1f[ct][1], acc, 0, 0, 0);
            d1[ct] = acc;
        }

        // ---- relu + transpose via swizzled LDS (wave-private, no barrier needed)
#pragma unroll
        for (int ct = 0; ct < 8; ct++)
#pragma unroll
            for (int r = 0; r < 4; r++)
                h1w[waddr[r] + ct * 16] = fmaxf(d1[ct][r], 0.0f);

        // ---- A2 fragments from LDS (2 x b128 per k-step, bank-floor-optimal)
        bf16x8 a2[4];
#pragma unroll
        for (int ks = 0; ks < 4; ks++) {
            f32x4 p0 = *(const f32x4*)&h1w[rbase0 + ks * 32];
            f32x4 p1 = *(const f32x4*)&h1w[rbase1 + ks * 32];
            a2[ks][0] = f2bf(p0[0]); a2[ks][1] = f2bf(p0[1]);
            a2[ks][2] = f2bf(p0[2]); a2[ks][3] = f2bf(p0[3]);
            a2[ks][4] = f2bf(p1[0]); a2[ks][5] = f2bf(p1[1]);
            a2[ks][6] = f2bf(p1[2]); a2[ks][7] = f2bf(p1[3]);
        }

        // ---- layer 2: D2[ct] = relu(h1) @ W2[:, ct*16..+16] + b2
        f32x4 d2[4];
#pragma unroll
        for (int ct = 0; ct < 4; ct++) {
            f32x4 acc = {b2v[ct], b2v[ct], b2v[ct], b2v[ct]};
#pragma unroll
            for (int ks = 0; ks < 4; ks++)
                acc = __builtin_amdgcn_mfma_f32_16x16x32_bf16(a2[ks], w2f[ct][ks], acc, 0, 0, 0);
            d2[ct] = acc;
        }

        // ---- layer 3 on VALU + 16-lane butterfly reduce + store
        float sr[4];
#pragma unroll
        for (int r = 0; r < 4; r++) {
            float s = 0.0f;
#pragma unroll
            for (int ct = 0; ct < 4; ct++)
                s = fmaf(fmaxf(d2[ct][r], 0.0f), wo[ct], s);
            sr[r] = s;
        }
#pragma unroll
        for (int m = 1; m <= 8; m <<= 1)
#pragma unroll
            for (int r = 0; r < 4; r++)
                sr[r] += __shfl_xor(sr[r], m);
        if (c == 0) {
            float4 o = {sr[0] + bo, sr[1] + bo, sr[2] + bo, sr[3] + bo};
            *(float4*)(out + tile * 16 + g * 4) = o;
        }
    }
}

extern "C" void kernel_launch(void* const* d_in, const int* in_sizes, int n_in,
                              void* d_out, int out_size, void* d_ws, size_t ws_size,
                              hipStream_t stream) {
    const float* X    = (const float*)d_in[0];
    const int*   z0   = (const int*)d_in[1];
    const int*   z1   = (const int*)d_in[2];
    const float* emb0 = (const float*)d_in[3];
    const float* emb1 = (const float*)d_in[4];
    const float* W1   = (const float*)d_in[5];
    const float* b1   = (const float*)d_in[6];
    const float* W2   = (const float*)d_in[7];
    const float* b2   = (const float*)d_in[8];
    const float* Wout = (const float*)d_in[9];
    const float* bout = (const float*)d_in[10];
    float* out = (float*)d_out;
    char* ws = (char*)d_ws;

    // Fixed region: cursors (NB int) + ovf (NB*16 f32) + means (NB*16 f32).
    const size_t fixed = (size_t)NB * 4 + (size_t)NB * 64 * 2;
    // Capacity ladder (deterministic, host-side); overflow path keeps every rung correct.
    const int c0s[5] = {32, 16, 12, 8, 4};
    const int c1s[5] = {64, 56, 40, 24, 8};
    int CAP0 = c0s[4], CAP1 = c1s[4];
    for (int i = 0; i < 5; i++) {
        size_t need = fixed + ((size_t)Q0 * c0s[i] + (size_t)Q1 * c1s[i]) * 32;
        if (need <= ws_size) { CAP0 = c0s[i]; CAP1 = c1s[i]; break; }
    }

    char* p = ws;
    uint32_t* bins0 = (uint32_t*)p;  p += (size_t)Q0 * CAP0 * 32;
    uint32_t* bins1 = (uint32_t*)p;  p += (size_t)Q1 * CAP1 * 32;
    uint32_t* zbase = (uint32_t*)p;
    int* cur0 = (int*)p;             p += (size_t)Q0 * 4;
    int* cur1 = (int*)p;             p += (size_t)Q1 * 4;
    float* ovf = (float*)p;          p += (size_t)NB * 64;
    float* means = (float*)p;

    const int zero_dwords = NB + NB * 16;    // cursors + ovf
    zero_ws_kernel<<<1024, 256, 0, stream>>>(zbase, zero_dwords);
    bin_kernel<<<(N_ROWS + 255) / 256, 256, 0, stream>>>(z0, z1, emb0, emb1,
                                                         bins0, bins1, cur0, cur1, ovf,
                                                         CAP0, CAP1);
    reduce_kernel<<<(NB * 64 + 255) / 256, 256, 0, stream>>>(bins0, bins1, cur0, cur1,
                                                             ovf, means, CAP0, CAP1);
    mlp_mfma_kernel<<<512, 256, 0, stream>>>(X, z0, z1, means, W1, b1, W2, b2,
                                             Wout, bout, out);
}